// Round 1
// baseline (29.110 us; speedup 1.0000x reference)
//
#include <hip/hip_runtime.h>

#define EDIM 10
#define CDIM 128
#define DDIM 9
#define BDIM 512
#define NT3 165   // #(a<=b<=c) triples over 9 dims
#define NT2 45    // #(a<=b) pairs
#define NT1 9
#define NT (NT3 + NT2 + NT1)  // 219

// ---------------------------------------------------------------------------
// Kernel 1: build per-(species, channel) symmetric coefficient table.
// T layout: [E][NT][CDIM][4] floats (component order: 0e, 1o_x, 1o_y, 1o_z).
// Permutation multiplicity (1/3/6 for order-3, 1/2 for order-2) is folded in.
// ---------------------------------------------------------------------------
__global__ __launch_bounds__(CDIM) void build_table_kernel(
    const float* __restrict__ u1_0e, const float* __restrict__ w1_0e,
    const float* __restrict__ u2_0e, const float* __restrict__ w2_0e,
    const float* __restrict__ u3_0e, const float* __restrict__ w3_0e,
    const float* __restrict__ u1_1o, const float* __restrict__ w1_1o,
    const float* __restrict__ u2_1o, const float* __restrict__ w2_1o,
    const float* __restrict__ u3_1o, const float* __restrict__ w3_1o,
    float* __restrict__ T) {
  const int c = threadIdx.x;           // channel
  const int blk = blockIdx.x;          // e * NT + t
  const int e = blk / NT;
  const int t = blk - e * NT;

  float o0 = 0.f, o1 = 0.f, o2 = 0.f, o3 = 0.f;

  if (t < NT3) {
    // decode t -> (a <= b <= cc)
    int tt = t, a = 0, b = 0;
    for (a = 0; a < DDIM; ++a) {
      int cnt = (DDIM - a) * (DDIM - a + 1) / 2;
      if (tt < cnt) break;
      tt -= cnt;
    }
    for (b = a; b < DDIM; ++b) {
      int cnt = DDIM - b;
      if (tt < cnt) break;
      tt -= cnt;
    }
    const int cc = b + tt;
    const float mult = (a == b && b == cc) ? 1.f : ((a == b || b == cc) ? 3.f : 6.f);

    const int ub0 = ((a * DDIM + b) * DDIM + cc) * 8;       // u3_0e: (9,9,9,8,1)
    for (int k = 0; k < 8; ++k)
      o0 += u3_0e[ub0 + k] * w3_0e[(k * EDIM + e) * CDIM + c];

    const int ub1 = ((a * DDIM + b) * DDIM + cc) * 12 * 3;  // u3_1o: (9,9,9,12,3)
    for (int k = 0; k < 12; ++k) {
      const float wv = w3_1o[(k * EDIM + e) * CDIM + c];
      o1 += u3_1o[ub1 + k * 3 + 0] * wv;
      o2 += u3_1o[ub1 + k * 3 + 1] * wv;
      o3 += u3_1o[ub1 + k * 3 + 2] * wv;
    }
    o0 *= mult; o1 *= mult; o2 *= mult; o3 *= mult;
  } else if (t < NT3 + NT2) {
    // decode (t - NT3) -> (a <= b)
    int tt = t - NT3, a = 0;
    for (a = 0; a < DDIM; ++a) {
      int cnt = DDIM - a;
      if (tt < cnt) break;
      tt -= cnt;
    }
    const int b = a + tt;
    const float mult = (a == b) ? 1.f : 2.f;

    const int ub0 = (a * DDIM + b) * 3;                     // u2_0e: (9,9,3,1)
    for (int k = 0; k < 3; ++k)
      o0 += u2_0e[ub0 + k] * w2_0e[(k * EDIM + e) * CDIM + c];

    const int ub1 = (a * DDIM + b) * 4 * 3;                 // u2_1o: (9,9,4,3)
    for (int k = 0; k < 4; ++k) {
      const float wv = w2_1o[(k * EDIM + e) * CDIM + c];
      o1 += u2_1o[ub1 + k * 3 + 0] * wv;
      o2 += u2_1o[ub1 + k * 3 + 1] * wv;
      o3 += u2_1o[ub1 + k * 3 + 2] * wv;
    }
    o0 *= mult; o1 *= mult; o2 *= mult; o3 *= mult;
  } else {
    const int j = t - NT3 - NT2;
    o0 = u1_0e[j] * w1_0e[e * CDIM + c];                    // u1_0e: (9,1,1), w1: (1,10,128)
    const float wv = w1_1o[e * CDIM + c];
    o1 = u1_1o[j * 3 + 0] * wv;                             // u1_1o: (9,1,3)
    o2 = u1_1o[j * 3 + 1] * wv;
    o3 = u1_1o[j * 3 + 2] * wv;
  }

  float4* dst = reinterpret_cast<float4*>(T) + (size_t)(e * NT + t) * CDIM + c;
  *dst = make_float4(o0, o1, o2, o3);
}

// ---------------------------------------------------------------------------
// Kernel 2: one thread per (b, c) pair. x row in registers; stream 219
// coalesced float4 table rows, 4 FMAs each. out[b][c][0:4] as one float4.
// ---------------------------------------------------------------------------
__global__ __launch_bounds__(256) void symcon_main_kernel(
    const float* __restrict__ x, const float* __restrict__ y,
    const float* __restrict__ T, float* __restrict__ out) {
  const int tid = threadIdx.x;
  const int c = tid & (CDIM - 1);
  const int b = blockIdx.x * 2 + (tid >> 7);

  // species = argmax of one-hot row (exact 0/1 values)
  int e = 0;
  for (int q = 0; q < EDIM; ++q)
    if (y[b * EDIM + q] > 0.5f) e = q;

  float xv[DDIM];
  const float* xb = x + ((size_t)b * CDIM + c) * DDIM;
#pragma unroll
  for (int j = 0; j < DDIM; ++j) xv[j] = xb[j];

  const float4* Tb = reinterpret_cast<const float4*>(T) + (size_t)e * NT * CDIM + c;

  float a0 = 0.f, a1 = 0.f, a2 = 0.f, a3 = 0.f;
  int t = 0;

  // order 3: sum over a<=b<=cc of T3 * x_a x_b x_cc
#pragma unroll
  for (int a = 0; a < DDIM; ++a) {
#pragma unroll
    for (int b2 = a; b2 < DDIM; ++b2) {
      const float xab = xv[a] * xv[b2];
#pragma unroll
      for (int c3 = b2; c3 < DDIM; ++c3) {
        const float m = xab * xv[c3];
        const float4 tv = Tb[(size_t)t * CDIM];
        a0 = fmaf(tv.x, m, a0);
        a1 = fmaf(tv.y, m, a1);
        a2 = fmaf(tv.z, m, a2);
        a3 = fmaf(tv.w, m, a3);
        ++t;
      }
    }
  }
  // order 2
#pragma unroll
  for (int a = 0; a < DDIM; ++a) {
#pragma unroll
    for (int b2 = a; b2 < DDIM; ++b2) {
      const float m = xv[a] * xv[b2];
      const float4 tv = Tb[(size_t)t * CDIM];
      a0 = fmaf(tv.x, m, a0);
      a1 = fmaf(tv.y, m, a1);
      a2 = fmaf(tv.z, m, a2);
      a3 = fmaf(tv.w, m, a3);
      ++t;
    }
  }
  // order 1
#pragma unroll
  for (int j = 0; j < DDIM; ++j) {
    const float m = xv[j];
    const float4 tv = Tb[(size_t)t * CDIM];
    a0 = fmaf(tv.x, m, a0);
    a1 = fmaf(tv.y, m, a1);
    a2 = fmaf(tv.z, m, a2);
    a3 = fmaf(tv.w, m, a3);
    ++t;
  }

  float4* o = reinterpret_cast<float4*>(out) + ((size_t)b * CDIM + c);
  *o = make_float4(a0, a1, a2, a3);
}

extern "C" void kernel_launch(void* const* d_in, const int* in_sizes, int n_in,
                              void* d_out, int out_size, void* d_ws, size_t ws_size,
                              hipStream_t stream) {
  const float* x     = (const float*)d_in[0];
  const float* y     = (const float*)d_in[1];
  const float* u1_0e = (const float*)d_in[2];
  const float* w1_0e = (const float*)d_in[3];
  const float* u2_0e = (const float*)d_in[4];
  const float* w2_0e = (const float*)d_in[5];
  const float* u3_0e = (const float*)d_in[6];
  const float* w3_0e = (const float*)d_in[7];
  const float* u1_1o = (const float*)d_in[8];
  const float* w1_1o = (const float*)d_in[9];
  const float* u2_1o = (const float*)d_in[10];
  const float* w2_1o = (const float*)d_in[11];
  const float* u3_1o = (const float*)d_in[12];
  const float* w3_1o = (const float*)d_in[13];

  const size_t table_bytes = (size_t)EDIM * NT * CDIM * 4 * sizeof(float);  // ~4.49 MB
  if (ws_size < table_bytes) return;  // workspace too small (not expected)
  float* T = (float*)d_ws;

  hipLaunchKernelGGL(build_table_kernel, dim3(EDIM * NT), dim3(CDIM), 0, stream,
                     u1_0e, w1_0e, u2_0e, w2_0e, u3_0e, w3_0e,
                     u1_1o, w1_1o, u2_1o, w2_1o, u3_1o, w3_1o, T);

  hipLaunchKernelGGL(symcon_main_kernel, dim3(BDIM / 2), dim3(256), 0, stream,
                     x, y, T, (float*)d_out);
}